// Round 3
// baseline (149.677 us; speedup 1.0000x reference)
//
#include <hip/hip_runtime.h>
#include <math.h>

#define H_   16
#define NB_  64
#define D_   1024
#define HID_ 64
#define B_   4
#define T_   2048
#define ROWS (B_*T_)    // 8192
#define HNB  (H_*NB_)   // 1024

__device__ __forceinline__ float gelu_exact(float x) {
    return 0.5f * x * (1.0f + erff(x * 0.7071067811865476f));
}
__device__ __forceinline__ float sigmoidf(float x) {
    return 1.0f / (1.0f + expf(-x));
}

// ---------------- Kernel 1: h = gelu(X @ W1 + b1) ----------------
__global__ __launch_bounds__(256) void k_gemm1(const float* __restrict__ X,
                                               const float* __restrict__ W1,
                                               const float* __restrict__ b1,
                                               float* __restrict__ hbuf) {
    __shared__ float xs[16][132];
    __shared__ float ws[128][64];
    const int t  = threadIdx.x;
    const int r0 = blockIdx.x * 16;
    const int r  = t >> 4;
    const int j4 = t & 15;
    float acc0 = 0.f, acc1 = 0.f, acc2 = 0.f, acc3 = 0.f;

    for (int c = 0; c < 8; ++c) {
        __syncthreads();
        #pragma unroll
        for (int q = 0; q < 2; ++q) {
            int s  = q * 256 + t;
            int rr = s >> 5;
            int kk = (s & 31) << 2;
            float4 v = *(const float4*)&X[(r0 + rr) * D_ + c * 128 + kk];
            *(float4*)&xs[rr][kk] = v;
        }
        #pragma unroll
        for (int q = 0; q < 8; ++q) {
            int s = q * 256 + t;
            float4 v = *(const float4*)&W1[c * 8192 + s * 4];
            int dd = s >> 4;
            int jj = (s & 15) << 2;
            *(float4*)&ws[dd][jj] = v;
        }
        __syncthreads();
        #pragma unroll 8
        for (int dd = 0; dd < 128; ++dd) {
            float  xv = xs[r][dd];
            float4 w  = *(const float4*)&ws[dd][j4 * 4];
            acc0 = fmaf(xv, w.x, acc0);
            acc1 = fmaf(xv, w.y, acc1);
            acc2 = fmaf(xv, w.z, acc2);
            acc3 = fmaf(xv, w.w, acc3);
        }
    }
    const int j = j4 * 4;
    float4 bb = *(const float4*)&b1[j];
    float4 hv;
    hv.x = gelu_exact(acc0 + bb.x);
    hv.y = gelu_exact(acc1 + bb.y);
    hv.z = gelu_exact(acc2 + bb.z);
    hv.w = gelu_exact(acc3 + bb.w);
    *(float4*)&hbuf[(r0 + r) * HID_ + j] = hv;
}

// ---------------- Kernel 2: gates = sigmoid(h @ W2 + b2) ----------------
// Also writes gatesT[(b*16+h)*64+nb][t] (transposed, for the scan) when
// gatesT != nullptr. Per thread: rows rq*4..rq*4+3 (consecutive t) x cols
// {k, k+1} -> two transposed float4 stores.
__global__ __launch_bounds__(256) void k_gemm2(const float* __restrict__ hbuf,
                                               const float* __restrict__ W2,
                                               const float* __restrict__ b2,
                                               float* __restrict__ gates,
                                               float* __restrict__ gatesT) {
    __shared__ float w2s[64][128];
    __shared__ float hs[16][64];
    const int t  = threadIdx.x;
    const int rb = blockIdx.x >> 3;
    const int kc = blockIdx.x & 7;
    const int r0 = rb * 16;
    const int k0 = kc * 128;

    #pragma unroll
    for (int q = 0; q < 8; ++q) {
        int s  = q * 256 + t;
        int j  = s >> 5;
        int kk = (s & 31) << 2;
        float4 v = *(const float4*)&W2[j * HNB + k0 + kk];
        *(float4*)&w2s[j][kk] = v;
    }
    {
        int rr = t >> 4;
        int jj = (t & 15) << 2;
        *(float4*)&hs[rr][jj] = *(const float4*)&hbuf[(r0 + rr) * HID_ + jj];
    }
    __syncthreads();

    const int kk2 = t & 63;
    const int rq  = t >> 6;
    float a00=0,a01=0,a10=0,a11=0,a20=0,a21=0,a30=0,a31=0;
    #pragma unroll 8
    for (int j = 0; j < 64; ++j) {
        float2 w = *(const float2*)&w2s[j][kk2 * 2];
        float h0 = hs[rq * 4 + 0][j];
        float h1 = hs[rq * 4 + 1][j];
        float h2 = hs[rq * 4 + 2][j];
        float h3 = hs[rq * 4 + 3][j];
        a00 = fmaf(h0, w.x, a00); a01 = fmaf(h0, w.y, a01);
        a10 = fmaf(h1, w.x, a10); a11 = fmaf(h1, w.y, a11);
        a20 = fmaf(h2, w.x, a20); a21 = fmaf(h2, w.y, a21);
        a30 = fmaf(h3, w.x, a30); a31 = fmaf(h3, w.y, a31);
    }
    const int k = k0 + kk2 * 2;
    float2 bb = *(const float2*)&b2[k];
    const int row = r0 + rq * 4;

    float s00 = sigmoidf(a00 + bb.x), s01 = sigmoidf(a01 + bb.y);
    float s10 = sigmoidf(a10 + bb.x), s11 = sigmoidf(a11 + bb.y);
    float s20 = sigmoidf(a20 + bb.x), s21 = sigmoidf(a21 + bb.y);
    float s30 = sigmoidf(a30 + bb.x), s31 = sigmoidf(a31 + bb.y);

    *(float2*)&gates[(row + 0) * HNB + k] = make_float2(s00, s01);
    *(float2*)&gates[(row + 1) * HNB + k] = make_float2(s10, s11);
    *(float2*)&gates[(row + 2) * HNB + k] = make_float2(s20, s21);
    *(float2*)&gates[(row + 3) * HNB + k] = make_float2(s30, s31);

    if (gatesT) {
        const int b  = r0 >> 11;            // r0 / 2048
        const int tt = (r0 & 2047) + rq * 4;
        size_t o0 = ((size_t)(b * 16 + (k >> 6)) * 64 + (k & 63)) * T_ + tt;
        size_t o1 = ((size_t)(b * 16 + ((k + 1) >> 6)) * 64 + ((k + 1) & 63)) * T_ + tt;
        *(float4*)&gatesT[o0] = make_float4(s00, s10, s20, s30);
        *(float4*)&gatesT[o1] = make_float4(s01, s11, s21, s31);
    }
}

// ---------------- Kernel T: fused square+scale+transpose (delta only) -------
// thsqT[(b*16+h)*64+nb][t] = Q*(delta*omega)^2
__global__ __launch_bounds__(256) void k_tr_delta(const float* __restrict__ delta,
                                                  const float* __restrict__ omega,
                                                  const float* __restrict__ log_Q,
                                                  float* __restrict__ thsqT) {
    const int tile = blockIdx.x;
    const int tt = tile & 31;
    const int bh = tile >> 5;     // 0..63
    const int h  = bh & 15;
    const int b  = bh >> 4;
    const int t0 = tt * 64;
    __shared__ float ld[64][66];
    const int tid = threadIdx.x;

    #pragma unroll
    for (int q = 0; q < 4; ++q) {
        int idx = q * 256 + tid;
        int row = idx >> 4;        // t offset 0..63
        int c4  = idx & 15;        // nb float4 idx
        size_t src = ((size_t)(b * T_ + t0 + row)) * HNB + h * NB_ + c4 * 4;
        float4 v = *(const float4*)&delta[src];
        ld[row][c4*4+0] = v.x; ld[row][c4*4+1] = v.y;
        ld[row][c4*4+2] = v.z; ld[row][c4*4+3] = v.w;
    }
    __syncthreads();
    #pragma unroll
    for (int q = 0; q < 4; ++q) {
        int idx = q * 256 + tid;
        int onb = idx >> 4;        // 0..63
        int ot4 = idx & 15;        // t float4 idx
        float om = omega[h * NB_ + onb];
        float Qv = expf(log_Q[h * NB_ + onb]);
        float sc = Qv * om * om;
        float d0 = ld[ot4*4+0][onb], d1 = ld[ot4*4+1][onb],
              d2 = ld[ot4*4+2][onb], d3 = ld[ot4*4+3][onb];
        float4 o;
        o.x = sc * d0 * d0; o.y = sc * d1 * d1;
        o.z = sc * d2 * d2; o.w = sc * d3 * d3;
        size_t obase = ((size_t)(bh * NB_ + onb)) * T_ + t0 + ot4 * 4;
        *(float4*)&thsqT[obase] = o;
    }
}

// ---------------- Kernel 3: scan, transposed in AND out, 4-deep prefetch ----
// grid 64 (b,h), block 64 (nb=lane). 16-step chunks, 4 register buffers.
// sigT may alias thsqT: chunk c is stored only after chunk c+3's loads were
// issued; loads always touch chunks strictly ahead of any store (distinct
// addresses), so in-place is race-free.
#define NCH16 (T_/16)   // 128

#define LD16(bt, bg, c) { \
    _Pragma("unroll") \
    for (int i = 0; i < 4; ++i) { \
        bt[i] = pth[(c) * 4 + i]; \
        bg[i] = pg [(c) * 4 + i]; \
    } }

#define STEP1(a, g, o) { \
    float aR  = (a) + R; \
    float s   = sigma + (a); \
    float den = sigma + aR; \
    float rc  = __builtin_amdgcn_rcpf(den); \
    float p   = fmaf(-(g), s, den); \
    sigma     = (s * p) * rc; \
    (o) = sigma; }

#define ST16(bt, bg, c) { \
    float4 so[4]; \
    _Pragma("unroll") \
    for (int i = 0; i < 4; ++i) { \
        STEP1(bt[i].x, bg[i].x, so[i].x); \
        STEP1(bt[i].y, bg[i].y, so[i].y); \
        STEP1(bt[i].z, bg[i].z, so[i].z); \
        STEP1(bt[i].w, bg[i].w, so[i].w); \
    } \
    _Pragma("unroll") \
    for (int i = 0; i < 4; ++i) pst[(c) * 4 + i] = so[i]; }

__global__ __launch_bounds__(64) void k_scan_t2(const float* thsqT,
                                                const float* gatesT,
                                                const float* __restrict__ log_R,
                                                const float* __restrict__ log_s0,
                                                float* sigT) {
    const int lane = threadIdx.x;
    const int bh   = blockIdx.x;
    const int h    = bh & 15;
    const int hn   = h * NB_ + lane;

    const float R = expf(log_R[hn]);
    float sigma   = expf(log_s0[hn]);

    const size_t chain = (size_t)(bh * NB_ + lane) * T_;
    const float4* pth = (const float4*)(thsqT + chain);
    const float4* pg  = (const float4*)(gatesT + chain);
    float4*       pst = (float4*)(sigT + chain);

    float4 t0v[4], g0v[4], t1v[4], g1v[4], t2v[4], g2v[4], t3v[4], g3v[4];
    LD16(t0v, g0v, 0);
    LD16(t1v, g1v, 1);
    LD16(t2v, g2v, 2);
    for (int c = 0; c < NCH16; c += 4) {
        if (c + 3 < NCH16) LD16(t3v, g3v, c + 3);
        ST16(t0v, g0v, c);
        if (c + 4 < NCH16) LD16(t0v, g0v, c + 4);
        ST16(t1v, g1v, c + 1);
        if (c + 5 < NCH16) LD16(t1v, g1v, c + 5);
        ST16(t2v, g2v, c + 2);
        if (c + 6 < NCH16) LD16(t2v, g2v, c + 6);
        ST16(t3v, g3v, c + 3);
    }
}

// ---------------- Kernel U: un-transpose sigma -> d_out layout ----------------
// sig_out[b][t][h][nb] = sigT[(b*16+h)*64+nb][t]
__global__ __launch_bounds__(256) void k_untr(const float* __restrict__ sigT,
                                              float* __restrict__ out) {
    const int tile = blockIdx.x;
    const int tt = tile & 31;
    const int bh = tile >> 5;
    const int h  = bh & 15;
    const int b  = bh >> 4;
    const int t0 = tt * 64;
    __shared__ float ls[64][65];
    const int tid = threadIdx.x;

    #pragma unroll
    for (int q = 0; q < 4; ++q) {
        int idx = q * 256 + tid;
        int row = idx >> 4;        // nb 0..63
        int c4  = idx & 15;        // t float4 idx
        float4 v = *(const float4*)&sigT[(size_t)(bh * NB_ + row) * T_ + t0 + c4 * 4];
        ls[row][c4*4+0] = v.x; ls[row][c4*4+1] = v.y;
        ls[row][c4*4+2] = v.z; ls[row][c4*4+3] = v.w;
    }
    __syncthreads();
    #pragma unroll
    for (int q = 0; q < 4; ++q) {
        int idx = q * 256 + tid;
        int tr  = idx >> 4;        // t offset 0..63
        int n4  = idx & 15;        // nb float4 idx
        float4 v;
        v.x = ls[n4*4+0][tr]; v.y = ls[n4*4+1][tr];
        v.z = ls[n4*4+2][tr]; v.w = ls[n4*4+3][tr];
        *(float4*)&out[((size_t)(b * T_ + t0 + tr)) * HNB + h * NB_ + n4 * 4] = v;
    }
}

// ---------------- Fallback scan (non-transposed), from R0 ----------------
#define SCAN_PF 32
#define LOADC(dv, gv, c) { \
    const int bofs_ = base + (c) * SCAN_PF * HNB; \
    _Pragma("unroll") \
    for (int i = 0; i < SCAN_PF; ++i) { \
        dv[i] = delta[bofs_ + i * HNB]; \
        gv[i] = gates[bofs_ + i * HNB]; \
    } }
#define COMPUTEC(dv, gv, c) { \
    const int bofs_ = base + (c) * SCAN_PF * HNB; \
    _Pragma("unroll") \
    for (int i = 0; i < SCAN_PF; ++i) { \
        float t0   = dv[i] * omq; \
        float qthR = fmaf(t0, t0, R); \
        float s    = fmaf(t0, t0, sigma); \
        float den  = sigma + qthR; \
        float rc   = __builtin_amdgcn_rcpf(den); \
        float p    = fmaf(-gv[i], s, den); \
        sigma      = (s * p) * rc; \
        sig_out[bofs_ + i * HNB] = sigma; \
    } }

__global__ __launch_bounds__(64) void k_scan(const float* __restrict__ delta,
                                             const float* __restrict__ omega,
                                             const float* __restrict__ log_Q,
                                             const float* __restrict__ log_R,
                                             const float* __restrict__ log_s0,
                                             const float* __restrict__ gates,
                                             float* __restrict__ sig_out) {
    const int lane = threadIdx.x;
    const int b    = blockIdx.x >> 4;
    const int h    = blockIdx.x & 15;
    const int hn   = h * NB_ + lane;

    const float om  = omega[hn];
    const float Q   = expf(log_Q[hn]);
    const float R   = expf(log_R[hn]);
    const float omq = om * sqrtf(Q);
    float sigma     = expf(log_s0[hn]);

    const int base = b * (T_ * HNB) + h * NB_ + lane;

    float dA[SCAN_PF], gA[SCAN_PF], dB[SCAN_PF], gB[SCAN_PF];
    LOADC(dA, gA, 0);
    const int NCH = T_ / SCAN_PF;
    for (int c = 0; c < NCH; c += 2) {
        LOADC(dB, gB, c + 1);
        COMPUTEC(dA, gA, c);
        if (c + 2 < NCH) LOADC(dA, gA, c + 2);
        COMPUTEC(dB, gB, c + 1);
    }
}

extern "C" void kernel_launch(void* const* d_in, const int* in_sizes, int n_in,
                              void* d_out, int out_size, void* d_ws, size_t ws_size,
                              hipStream_t stream) {
    const float* delta   = (const float*)d_in[0];
    const float* content = (const float*)d_in[1];
    const float* omega   = (const float*)d_in[2];
    const float* log_Q   = (const float*)d_in[3];
    const float* log_R   = (const float*)d_in[4];
    const float* log_s0  = (const float*)d_in[5];
    const float* W1      = (const float*)d_in[6];
    const float* b1      = (const float*)d_in[7];
    const float* W2      = (const float*)d_in[8];
    const float* b2      = (const float*)d_in[9];

    float* sig_out   = (float*)d_out;                    // 8388608 floats
    float* gates_out = sig_out + (size_t)ROWS * HNB;     // next 8388608

    const size_t n_sig = (size_t)ROWS * HNB;             // 8388608
    const size_t n_h   = (size_t)ROWS * HID_;            // 524288
    const size_t need_fast = (2 * n_sig + n_h) * sizeof(float);  // ~69 MB

    if (ws_size >= need_fast) {
        float* thsqT  = (float*)d_ws;        // also reused as sigT (in-place)
        float* gatesT = thsqT + n_sig;
        float* hbuf   = gatesT + n_sig;
        k_gemm1<<<ROWS / 16, 256, 0, stream>>>(content, W1, b1, hbuf);
        k_gemm2<<<(ROWS / 16) * 8, 256, 0, stream>>>(hbuf, W2, b2, gates_out, gatesT);
        k_tr_delta<<<B_ * H_ * 32, 256, 0, stream>>>(delta, omega, log_Q, thsqT);
        k_scan_t2<<<B_ * H_, 64, 0, stream>>>(thsqT, gatesT, log_R, log_s0, thsqT);
        k_untr<<<B_ * H_ * 32, 256, 0, stream>>>(thsqT, sig_out);
    } else {
        float* hbuf = (ws_size >= n_h * sizeof(float)) ? (float*)d_ws : sig_out;
        k_gemm1<<<ROWS / 16, 256, 0, stream>>>(content, W1, b1, hbuf);
        k_gemm2<<<(ROWS / 16) * 8, 256, 0, stream>>>(hbuf, W2, b2, gates_out, nullptr);
        k_scan<<<B_ * H_, 64, 0, stream>>>(delta, omega, log_Q, log_R, log_s0,
                                           gates_out, sig_out);
    }
}

// Round 4
// 117.016 us; speedup vs baseline: 1.2791x; 1.2791x over previous
//
#include <hip/hip_runtime.h>
#include <math.h>

#define H_   16
#define NB_  64
#define D_   1024
#define HID_ 64
#define B_   4
#define T_   2048
#define ROWS (B_*T_)    // 8192
#define HNB  (H_*NB_)   // 1024

__device__ __forceinline__ float gelu_exact(float x) {
    return 0.5f * x * (1.0f + erff(x * 0.7071067811865476f));
}
__device__ __forceinline__ float sigmoidf(float x) {
    return 1.0f / (1.0f + expf(-x));
}

// ---------------- Kernel 1: h = gelu(X @ W1 + b1) ----------------
__global__ __launch_bounds__(256) void k_gemm1(const float* __restrict__ X,
                                               const float* __restrict__ W1,
                                               const float* __restrict__ b1,
                                               float* __restrict__ hbuf) {
    __shared__ float xs[16][132];
    __shared__ float ws[128][64];
    const int t  = threadIdx.x;
    const int r0 = blockIdx.x * 16;
    const int r  = t >> 4;
    const int j4 = t & 15;
    float acc0 = 0.f, acc1 = 0.f, acc2 = 0.f, acc3 = 0.f;

    for (int c = 0; c < 8; ++c) {
        __syncthreads();
        #pragma unroll
        for (int q = 0; q < 2; ++q) {
            int s  = q * 256 + t;
            int rr = s >> 5;
            int kk = (s & 31) << 2;
            float4 v = *(const float4*)&X[(r0 + rr) * D_ + c * 128 + kk];
            *(float4*)&xs[rr][kk] = v;
        }
        #pragma unroll
        for (int q = 0; q < 8; ++q) {
            int s = q * 256 + t;
            float4 v = *(const float4*)&W1[c * 8192 + s * 4];
            int dd = s >> 4;
            int jj = (s & 15) << 2;
            *(float4*)&ws[dd][jj] = v;
        }
        __syncthreads();
        #pragma unroll 8
        for (int dd = 0; dd < 128; ++dd) {
            float  xv = xs[r][dd];
            float4 w  = *(const float4*)&ws[dd][j4 * 4];
            acc0 = fmaf(xv, w.x, acc0);
            acc1 = fmaf(xv, w.y, acc1);
            acc2 = fmaf(xv, w.z, acc2);
            acc3 = fmaf(xv, w.w, acc3);
        }
    }
    const int j = j4 * 4;
    float4 bb = *(const float4*)&b1[j];
    float4 hv;
    hv.x = gelu_exact(acc0 + bb.x);
    hv.y = gelu_exact(acc1 + bb.y);
    hv.z = gelu_exact(acc2 + bb.z);
    hv.w = gelu_exact(acc3 + bb.w);
    *(float4*)&hbuf[(r0 + r) * HID_ + j] = hv;
}

// ---------------- Kernel 2: gates = sigmoid(h @ W2 + b2) ----------------
__global__ __launch_bounds__(256) void k_gemm2(const float* __restrict__ hbuf,
                                               const float* __restrict__ W2,
                                               const float* __restrict__ b2,
                                               float* __restrict__ gates) {
    __shared__ float w2s[64][128];
    __shared__ float hs[16][64];
    const int t  = threadIdx.x;
    const int rb = blockIdx.x >> 3;
    const int kc = blockIdx.x & 7;
    const int r0 = rb * 16;
    const int k0 = kc * 128;

    #pragma unroll
    for (int q = 0; q < 8; ++q) {
        int s  = q * 256 + t;
        int j  = s >> 5;
        int kk = (s & 31) << 2;
        float4 v = *(const float4*)&W2[j * HNB + k0 + kk];
        *(float4*)&w2s[j][kk] = v;
    }
    {
        int rr = t >> 4;
        int jj = (t & 15) << 2;
        *(float4*)&hs[rr][jj] = *(const float4*)&hbuf[(r0 + rr) * HID_ + jj];
    }
    __syncthreads();

    const int kk2 = t & 63;
    const int rq  = t >> 6;
    float a00=0,a01=0,a10=0,a11=0,a20=0,a21=0,a30=0,a31=0;
    #pragma unroll 8
    for (int j = 0; j < 64; ++j) {
        float2 w = *(const float2*)&w2s[j][kk2 * 2];
        float h0 = hs[rq * 4 + 0][j];
        float h1 = hs[rq * 4 + 1][j];
        float h2 = hs[rq * 4 + 2][j];
        float h3 = hs[rq * 4 + 3][j];
        a00 = fmaf(h0, w.x, a00); a01 = fmaf(h0, w.y, a01);
        a10 = fmaf(h1, w.x, a10); a11 = fmaf(h1, w.y, a11);
        a20 = fmaf(h2, w.x, a20); a21 = fmaf(h2, w.y, a21);
        a30 = fmaf(h3, w.x, a30); a31 = fmaf(h3, w.y, a31);
    }
    const int k = k0 + kk2 * 2;
    float2 bb = *(const float2*)&b2[k];
    const int row = r0 + rq * 4;
    float2 o;
    o.x = sigmoidf(a00 + bb.x); o.y = sigmoidf(a01 + bb.y);
    *(float2*)&gates[(row + 0) * HNB + k] = o;
    o.x = sigmoidf(a10 + bb.x); o.y = sigmoidf(a11 + bb.y);
    *(float2*)&gates[(row + 1) * HNB + k] = o;
    o.x = sigmoidf(a20 + bb.x); o.y = sigmoidf(a21 + bb.y);
    *(float2*)&gates[(row + 2) * HNB + k] = o;
    o.x = sigmoidf(a30 + bb.x); o.y = sigmoidf(a31 + bb.y);
    *(float2*)&gates[(row + 3) * HNB + k] = o;
}

// ---------------- Kernel 3: fused producer-consumer scan ----------------
// grid 64 (b,h) x 256 threads. Wave 0 scans 64 chains (lane = nb) from LDS;
// waves 1-3 prefetch the next 128-step tile from natural-layout delta/gates,
// double-buffered + barrier-synced (compiler cannot sink cross-wave loads).
// LDS tile row t holds interleaved {aR, g} pairs for nb=0..63, where
// aR = Q*(delta*omega)^2 + R precomputed by the loaders.
// 2*128*128*4B = 128 KiB static LDS (size verified working on gfx950).
#define TT_ 128
#define NT_ (T_/TT_)   // 16

// one scan step: den = sigma + aR; s = den - R (= sigma + Q*th^2);
// pp = den - g*s; sigma' = s*pp/den   (== s*(1 - g*s/(s+R)))
#define FSTEP(q, ofs) { \
    float den = sigma + (q).x; \
    float rc  = __builtin_amdgcn_rcpf(den); \
    float s   = den - R; \
    float pp  = fmaf(-(q).y, s, den); \
    sigma     = (s * pp) * rc; \
    op[(ofs) * 1024] = sigma; }

__global__ __launch_bounds__(256) void k_scan_fused(
        const float* __restrict__ delta,
        const float* __restrict__ gates,
        const float* __restrict__ omega,
        const float* __restrict__ log_Q,
        const float* __restrict__ log_R,
        const float* __restrict__ log_s0,
        float* __restrict__ sig) {
    __shared__ float tg[2][TT_][128];   // {aR, g} interleaved, 128 KiB
    const int tid = threadIdx.x;
    const int bh  = blockIdx.x;
    const int b   = bh >> 4;
    const int h   = bh & 15;
    const size_t base = (size_t)b * T_ * HNB + h * NB_;   // elem ofs of (b,0,h,0)

    if (tid < 64) {
        // ---------- scan wave ----------
        const int lane = tid;
        const int hn   = h * NB_ + lane;
        const float R  = expf(log_R[hn]);
        float sigma    = expf(log_s0[hn]);
        float* outp    = sig + base + lane;

        __syncthreads();               // tile 0 ready
        for (int i = 0; i < NT_; ++i) {
            const float* bufp = &tg[i & 1][0][2 * lane];
            float* op = outp + (size_t)i * TT_ * HNB;
            for (int r = 0; r < TT_; r += 4) {
                float2 q0 = *(const float2*)(bufp + (r + 0) * 128);
                float2 q1 = *(const float2*)(bufp + (r + 1) * 128);
                float2 q2 = *(const float2*)(bufp + (r + 2) * 128);
                float2 q3 = *(const float2*)(bufp + (r + 3) * 128);
                FSTEP(q0, r + 0);
                FSTEP(q1, r + 1);
                FSTEP(q2, r + 2);
                FSTEP(q3, r + 3);
            }
            __syncthreads();           // release buf to loaders / get next
        }
    } else {
        // ---------- loader waves (192 threads) ----------
        const int ltid = tid - 64;      // 0..191
        const int col4 = ltid & 15;     // fixed float4 column (nb = col4*4..+3)
        const int rgrp = ltid >> 4;     // 0..11 (12 rows per iteration)
        const int hn4  = h * NB_ + col4 * 4;

        float4 om4 = *(const float4*)&omega[hn4];
        float4 lq4 = *(const float4*)&log_Q[hn4];
        float4 lr4 = *(const float4*)&log_R[hn4];
        const float sc0 = expf(lq4.x) * om4.x * om4.x;
        const float sc1 = expf(lq4.y) * om4.y * om4.y;
        const float sc2 = expf(lq4.z) * om4.z * om4.z;
        const float sc3 = expf(lq4.w) * om4.w * om4.w;
        const float R0 = expf(lr4.x), R1 = expf(lr4.y);
        const float R2 = expf(lr4.z), R3 = expf(lr4.w);

        const float* dp = delta + base + col4 * 4;
        const float* gp = gates + base + col4 * 4;

        // prologue: tile 0 -> buf 0
        for (int it = 0; it < 11; ++it) {
            int row = it * 12 + rgrp;
            if (row < TT_) {
                float4 d = *(const float4*)&dp[(size_t)row * HNB];
                float4 g = *(const float4*)&gp[(size_t)row * HNB];
                float* wrow = &tg[0][row][8 * col4];
                *(float2*)&wrow[0] = make_float2(fmaf(sc0 * d.x, d.x, R0), g.x);
                *(float2*)&wrow[2] = make_float2(fmaf(sc1 * d.y, d.y, R1), g.y);
                *(float2*)&wrow[4] = make_float2(fmaf(sc2 * d.z, d.z, R2), g.z);
                *(float2*)&wrow[6] = make_float2(fmaf(sc3 * d.w, d.w, R3), g.w);
            }
        }
        __syncthreads();               // tile 0 ready

        for (int i = 0; i < NT_; ++i) {
            if (i + 1 < NT_) {
                const int buf = (i + 1) & 1;
                const size_t t0 = (size_t)(i + 1) * TT_;
                for (int it = 0; it < 11; ++it) {
                    int row = it * 12 + rgrp;
                    if (row < TT_) {
                        float4 d = *(const float4*)&dp[(t0 + row) * HNB];
                        float4 g = *(const float4*)&gp[(t0 + row) * HNB];
                        float* wrow = &tg[buf][row][8 * col4];
                        *(float2*)&wrow[0] = make_float2(fmaf(sc0 * d.x, d.x, R0), g.x);
                        *(float2*)&wrow[2] = make_float2(fmaf(sc1 * d.y, d.y, R1), g.y);
                        *(float2*)&wrow[4] = make_float2(fmaf(sc2 * d.z, d.z, R2), g.z);
                        *(float2*)&wrow[6] = make_float2(fmaf(sc3 * d.w, d.w, R3), g.w);
                    }
                }
            }
            __syncthreads();
        }
    }
}

extern "C" void kernel_launch(void* const* d_in, const int* in_sizes, int n_in,
                              void* d_out, int out_size, void* d_ws, size_t ws_size,
                              hipStream_t stream) {
    const float* delta   = (const float*)d_in[0];
    const float* content = (const float*)d_in[1];
    const float* omega   = (const float*)d_in[2];
    const float* log_Q   = (const float*)d_in[3];
    const float* log_R   = (const float*)d_in[4];
    const float* log_s0  = (const float*)d_in[5];
    const float* W1      = (const float*)d_in[6];
    const float* b1      = (const float*)d_in[7];
    const float* W2      = (const float*)d_in[8];
    const float* b2      = (const float*)d_in[9];

    float* sig_out   = (float*)d_out;                    // 8388608 floats
    float* gates_out = sig_out + (size_t)ROWS * HNB;     // next 8388608

    const size_t n_h = (size_t)ROWS * HID_;              // 524288
    // h scratch: workspace if available, else sigma region of d_out (it is
    // fully overwritten by k_scan_fused afterwards, stream-ordered).
    float* hbuf = (ws_size >= n_h * sizeof(float)) ? (float*)d_ws : sig_out;

    k_gemm1<<<ROWS / 16, 256, 0, stream>>>(content, W1, b1, hbuf);
    k_gemm2<<<(ROWS / 16) * 8, 256, 0, stream>>>(hbuf, W2, b2, gates_out);
    k_scan_fused<<<B_ * H_, 256, 0, stream>>>(delta, gates_out, omega,
                                              log_Q, log_R, log_s0, sig_out);
}

// Round 5
// 108.243 us; speedup vs baseline: 1.3828x; 1.0810x over previous
//
#include <hip/hip_runtime.h>
#include <math.h>

#define H_   16
#define NB_  64
#define D_   1024
#define HID_ 64
#define B_   4
#define T_   2048
#define ROWS (B_*T_)    // 8192
#define HNB  (H_*NB_)   // 1024

__device__ __forceinline__ float gelu_exact(float x) {
    return 0.5f * x * (1.0f + erff(x * 0.7071067811865476f));
}
__device__ __forceinline__ float sigmoidf(float x) {
    return 1.0f / (1.0f + expf(-x));
}

// ---------------- Kernel 1: h = gelu(X @ W1 + b1) ----------------
__global__ __launch_bounds__(256) void k_gemm1(const float* __restrict__ X,
                                               const float* __restrict__ W1,
                                               const float* __restrict__ b1,
                                               float* __restrict__ hbuf) {
    __shared__ float xs[16][132];
    __shared__ float ws[128][64];
    const int t  = threadIdx.x;
    const int r0 = blockIdx.x * 16;
    const int r  = t >> 4;
    const int j4 = t & 15;
    float acc0 = 0.f, acc1 = 0.f, acc2 = 0.f, acc3 = 0.f;

    for (int c = 0; c < 8; ++c) {
        __syncthreads();
        #pragma unroll
        for (int q = 0; q < 2; ++q) {
            int s  = q * 256 + t;
            int rr = s >> 5;
            int kk = (s & 31) << 2;
            float4 v = *(const float4*)&X[(r0 + rr) * D_ + c * 128 + kk];
            *(float4*)&xs[rr][kk] = v;
        }
        #pragma unroll
        for (int q = 0; q < 8; ++q) {
            int s = q * 256 + t;
            float4 v = *(const float4*)&W1[c * 8192 + s * 4];
            int dd = s >> 4;
            int jj = (s & 15) << 2;
            *(float4*)&ws[dd][jj] = v;
        }
        __syncthreads();
        #pragma unroll 8
        for (int dd = 0; dd < 128; ++dd) {
            float  xv = xs[r][dd];
            float4 w  = *(const float4*)&ws[dd][j4 * 4];
            acc0 = fmaf(xv, w.x, acc0);
            acc1 = fmaf(xv, w.y, acc1);
            acc2 = fmaf(xv, w.z, acc2);
            acc3 = fmaf(xv, w.w, acc3);
        }
    }
    const int j = j4 * 4;
    float4 bb = *(const float4*)&b1[j];
    float4 hv;
    hv.x = gelu_exact(acc0 + bb.x);
    hv.y = gelu_exact(acc1 + bb.y);
    hv.z = gelu_exact(acc2 + bb.z);
    hv.w = gelu_exact(acc3 + bb.w);
    *(float4*)&hbuf[(r0 + r) * HID_ + j] = hv;
}

// ---------------- Kernel 2: gates = sigmoid(h @ W2 + b2) ----------------
__global__ __launch_bounds__(256) void k_gemm2(const float* __restrict__ hbuf,
                                               const float* __restrict__ W2,
                                               const float* __restrict__ b2,
                                               float* __restrict__ gates) {
    __shared__ float w2s[64][128];
    __shared__ float hs[16][64];
    const int t  = threadIdx.x;
    const int rb = blockIdx.x >> 3;
    const int kc = blockIdx.x & 7;
    const int r0 = rb * 16;
    const int k0 = kc * 128;

    #pragma unroll
    for (int q = 0; q < 8; ++q) {
        int s  = q * 256 + t;
        int j  = s >> 5;
        int kk = (s & 31) << 2;
        float4 v = *(const float4*)&W2[j * HNB + k0 + kk];
        *(float4*)&w2s[j][kk] = v;
    }
    {
        int rr = t >> 4;
        int jj = (t & 15) << 2;
        *(float4*)&hs[rr][jj] = *(const float4*)&hbuf[(r0 + rr) * HID_ + jj];
    }
    __syncthreads();

    const int kk2 = t & 63;
    const int rq  = t >> 6;
    float a00=0,a01=0,a10=0,a11=0,a20=0,a21=0,a30=0,a31=0;
    #pragma unroll 8
    for (int j = 0; j < 64; ++j) {
        float2 w = *(const float2*)&w2s[j][kk2 * 2];
        float h0 = hs[rq * 4 + 0][j];
        float h1 = hs[rq * 4 + 1][j];
        float h2 = hs[rq * 4 + 2][j];
        float h3 = hs[rq * 4 + 3][j];
        a00 = fmaf(h0, w.x, a00); a01 = fmaf(h0, w.y, a01);
        a10 = fmaf(h1, w.x, a10); a11 = fmaf(h1, w.y, a11);
        a20 = fmaf(h2, w.x, a20); a21 = fmaf(h2, w.y, a21);
        a30 = fmaf(h3, w.x, a30); a31 = fmaf(h3, w.y, a31);
    }
    const int k = k0 + kk2 * 2;
    float2 bb = *(const float2*)&b2[k];
    const int row = r0 + rq * 4;
    float2 o;
    o.x = sigmoidf(a00 + bb.x); o.y = sigmoidf(a01 + bb.y);
    *(float2*)&gates[(row + 0) * HNB + k] = o;
    o.x = sigmoidf(a10 + bb.x); o.y = sigmoidf(a11 + bb.y);
    *(float2*)&gates[(row + 1) * HNB + k] = o;
    o.x = sigmoidf(a20 + bb.x); o.y = sigmoidf(a21 + bb.y);
    *(float2*)&gates[(row + 2) * HNB + k] = o;
    o.x = sigmoidf(a30 + bb.x); o.y = sigmoidf(a31 + bb.y);
    *(float2*)&gates[(row + 3) * HNB + k] = o;
}

// ---------------- Kernel 3: producer-consumer scan, v2 ----------------
// grid 64 (b,h) x 256 threads, 1 block/CU (96 KiB LDS).
// Roles: wave0 = scan (64 chains, lane=nb, ONLY the dep chain + LDS ops);
//        wave1 = delta loader (computes aR = Q*(d*om)^2 + R);
//        wave2 = gates loader; wave3 = sigma storer (LDS -> coalesced global).
// Phase pipeline (one barrier per phase, p = 0..NPH+1):
//   loaders: load tile p      -> tg buf p&1        (p <  NPH)
//   scan:    compute tile p-1 from buf (p-1)&1 -> sg buf (p-1)&1 (1<=p<=NPH)
//   storer:  store  tile p-2 from sg buf p&1      (p >= 2)
#define TT_  64
#define NPH  (T_/TT_)   // 32

#define LD8(A, G, grp) { \
    _Pragma("unroll") \
    for (int u = 0; u < 8; ++u) { \
        A[u] = pa[((grp)*8 + u) * 64]; \
        G[u] = pg[((grp)*8 + u) * 64]; \
    } }

#define CP8(A, G, grp) { \
    _Pragma("unroll") \
    for (int u = 0; u < 8; ++u) { \
        float den = sigma + A[u]; \
        float rc  = __builtin_amdgcn_rcpf(den); \
        float s   = den - R; \
        float pp  = fmaf(-G[u], s, den); \
        sigma     = (s * pp) * rc; \
        ps[((grp)*8 + u) * 64] = sigma; \
    } }

__global__ __launch_bounds__(256) void k_scan_fused2(
        const float* __restrict__ delta,
        const float* __restrict__ gates,
        const float* __restrict__ omega,
        const float* __restrict__ log_Q,
        const float* __restrict__ log_R,
        const float* __restrict__ log_s0,
        float* __restrict__ sig) {
    __shared__ float aR_lds[2][TT_][64];   // 32 KiB
    __shared__ float g_lds [2][TT_][64];   // 32 KiB
    __shared__ float sg_lds[2][TT_][64];   // 32 KiB
    const int tid = threadIdx.x;
    const int bh  = blockIdx.x;
    const int b   = bh >> 4;
    const int h   = bh & 15;
    const size_t base = (size_t)b * T_ * HNB + h * NB_;   // elem ofs of (b,0,h,0)
    const int wv   = tid >> 6;      // 0..3
    const int lane = tid & 63;

    // ---- per-role setup (no barriers inside) ----
    float R = 0.f, sigma = 0.f;                      // wave0
    float sc0=0,sc1=0,sc2=0,sc3=0,Rr0=0,Rr1=0,Rr2=0,Rr3=0;  // wave1
    const int col4 = lane & 15;
    const int rg   = lane >> 4;
    const float* dp = delta + base + col4 * 4;
    const float* gp = gates + base + col4 * 4;

    if (wv == 0) {
        const int hn = h * NB_ + lane;
        R     = expf(log_R[hn]);
        sigma = expf(log_s0[hn]);
    } else if (wv == 1) {
        const int hn4 = h * NB_ + col4 * 4;
        float4 om4 = *(const float4*)&omega[hn4];
        float4 lq4 = *(const float4*)&log_Q[hn4];
        float4 lr4 = *(const float4*)&log_R[hn4];
        sc0 = expf(lq4.x) * om4.x * om4.x;
        sc1 = expf(lq4.y) * om4.y * om4.y;
        sc2 = expf(lq4.z) * om4.z * om4.z;
        sc3 = expf(lq4.w) * om4.w * om4.w;
        Rr0 = expf(lr4.x); Rr1 = expf(lr4.y);
        Rr2 = expf(lr4.z); Rr3 = expf(lr4.w);
    }

    for (int p = 0; p <= NPH + 1; ++p) {
        if (wv == 0) {
            if (p >= 1 && p <= NPH) {
                const int buf = (p - 1) & 1;
                const float* pa = &aR_lds[buf][0][lane];
                const float* pg = &g_lds [buf][0][lane];
                float*       ps = &sg_lds[buf][0][lane];
                float a0[8], g0[8], a1[8], g1[8];
                LD8(a0, g0, 0);
                LD8(a1, g1, 1);
                CP8(a0, g0, 0); LD8(a0, g0, 2);
                CP8(a1, g1, 1); LD8(a1, g1, 3);
                CP8(a0, g0, 2); LD8(a0, g0, 4);
                CP8(a1, g1, 3); LD8(a1, g1, 5);
                CP8(a0, g0, 4); LD8(a0, g0, 6);
                CP8(a1, g1, 5); LD8(a1, g1, 7);
                CP8(a0, g0, 6);
                CP8(a1, g1, 7);
            }
        } else if (wv == 1) {
            if (p < NPH) {
                const int buf = p & 1;
                const size_t t0 = (size_t)p * TT_;
                #pragma unroll
                for (int it = 0; it < 16; ++it) {
                    const int row = it * 4 + rg;
                    float4 d = *(const float4*)&dp[(t0 + row) * HNB];
                    float4 a;
                    a.x = fmaf(sc0 * d.x, d.x, Rr0);
                    a.y = fmaf(sc1 * d.y, d.y, Rr1);
                    a.z = fmaf(sc2 * d.z, d.z, Rr2);
                    a.w = fmaf(sc3 * d.w, d.w, Rr3);
                    *(float4*)&aR_lds[buf][row][col4 * 4] = a;
                }
            }
        } else if (wv == 2) {
            if (p < NPH) {
                const int buf = p & 1;
                const size_t t0 = (size_t)p * TT_;
                #pragma unroll
                for (int it = 0; it < 16; ++it) {
                    const int row = it * 4 + rg;
                    float4 g = *(const float4*)&gp[(t0 + row) * HNB];
                    *(float4*)&g_lds[buf][row][col4 * 4] = g;
                }
            }
        } else {
            if (p >= 2) {
                const int buf = p & 1;
                const size_t t0 = (size_t)(p - 2) * TT_;
                float* op = sig + base + col4 * 4;
                #pragma unroll
                for (int it = 0; it < 16; ++it) {
                    const int row = it * 4 + rg;
                    float4 v = *(const float4*)&sg_lds[buf][row][col4 * 4];
                    *(float4*)&op[(t0 + row) * HNB] = v;
                }
            }
        }
        __syncthreads();
    }
}

// ---------------- Fallback scan (non-transposed), from R0 ----------------
#define SCAN_PF 32
#define LOADC(dv, gv, c) { \
    const int bofs_ = base + (c) * SCAN_PF * HNB; \
    _Pragma("unroll") \
    for (int i = 0; i < SCAN_PF; ++i) { \
        dv[i] = delta[bofs_ + i * HNB]; \
        gv[i] = gates[bofs_ + i * HNB]; \
    } }
#define COMPUTEC(dv, gv, c) { \
    const int bofs_ = base + (c) * SCAN_PF * HNB; \
    _Pragma("unroll") \
    for (int i = 0; i < SCAN_PF; ++i) { \
        float t0   = dv[i] * omq; \
        float qthR = fmaf(t0, t0, R); \
        float s    = fmaf(t0, t0, sigma); \
        float den  = sigma + qthR; \
        float rc   = __builtin_amdgcn_rcpf(den); \
        float p    = fmaf(-gv[i], s, den); \
        sigma      = (s * p) * rc; \
        sig_out[bofs_ + i * HNB] = sigma; \
    } }

__global__ __launch_bounds__(64) void k_scan(const float* __restrict__ delta,
                                             const float* __restrict__ omega,
                                             const float* __restrict__ log_Q,
                                             const float* __restrict__ log_R,
                                             const float* __restrict__ log_s0,
                                             const float* __restrict__ gates,
                                             float* __restrict__ sig_out) {
    const int lane = threadIdx.x;
    const int b    = blockIdx.x >> 4;
    const int h    = blockIdx.x & 15;
    const int hn   = h * NB_ + lane;

    const float om  = omega[hn];
    const float Q   = expf(log_Q[hn]);
    const float R   = expf(log_R[hn]);
    const float omq = om * sqrtf(Q);
    float sigma     = expf(log_s0[hn]);

    const int base = b * (T_ * HNB) + h * NB_ + lane;

    float dA[SCAN_PF], gA[SCAN_PF], dB[SCAN_PF], gB[SCAN_PF];
    LOADC(dA, gA, 0);
    const int NCH = T_ / SCAN_PF;
    for (int c = 0; c < NCH; c += 2) {
        LOADC(dB, gB, c + 1);
        COMPUTEC(dA, gA, c);
        if (c + 2 < NCH) LOADC(dA, gA, c + 2);
        COMPUTEC(dB, gB, c + 1);
    }
}

extern "C" void kernel_launch(void* const* d_in, const int* in_sizes, int n_in,
                              void* d_out, int out_size, void* d_ws, size_t ws_size,
                              hipStream_t stream) {
    const float* delta   = (const float*)d_in[0];
    const float* content = (const float*)d_in[1];
    const float* omega   = (const float*)d_in[2];
    const float* log_Q   = (const float*)d_in[3];
    const float* log_R   = (const float*)d_in[4];
    const float* log_s0  = (const float*)d_in[5];
    const float* W1      = (const float*)d_in[6];
    const float* b1      = (const float*)d_in[7];
    const float* W2      = (const float*)d_in[8];
    const float* b2      = (const float*)d_in[9];

    float* sig_out   = (float*)d_out;                    // 8388608 floats
    float* gates_out = sig_out + (size_t)ROWS * HNB;     // next 8388608

    const size_t n_h = (size_t)ROWS * HID_;              // 524288
    // h scratch: workspace if available, else sigma region of d_out (fully
    // overwritten by the scan afterwards, stream-ordered).
    float* hbuf = (ws_size >= n_h * sizeof(float)) ? (float*)d_ws : sig_out;

    k_gemm1<<<ROWS / 16, 256, 0, stream>>>(content, W1, b1, hbuf);
    k_gemm2<<<(ROWS / 16) * 8, 256, 0, stream>>>(hbuf, W2, b2, gates_out);
    k_scan_fused2<<<B_ * H_, 256, 0, stream>>>(delta, gates_out, omega,
                                               log_Q, log_R, log_s0, sig_out);
}